// Round 2
// baseline (171.203 us; speedup 1.0000x reference)
//
#include <hip/hip_runtime.h>
#include <math.h>

// Problem constants
#define B_   16
#define C_   128
#define H_   32
#define W_   32
#define D_   64
#define K_   8192
#define HW_  (H_*W_)       // 1024
#define N_   (B_*HW_)      // 16384

// Megasweep config: 1 block per 64 rows, block streams ALL K codes twice
// (pass1 = max, pass2 = push) through a double-buffered LDS.
// CHUNK=256 -> EB 64 KB, total static LDS ~77 KB (proven-safe budget;
// R1's 146 KB variant may have failed launch).
#define ROWS     64                // rows per block
#define CHUNK    256               // codes per LDS chunk (32 KB bf16)
#define NCH      (K_/CHUNK)        // 32 chunks per pass
#define MARGIN   0.12f             // worst-case bf16 screen bound (R5-verified)
#define CAND_CAP 32

typedef short v8s __attribute__((ext_vector_type(8)));
typedef float v4f __attribute__((ext_vector_type(4)));

__device__ __forceinline__ short f2bf(float f) {   // RNE fp32 -> bf16
    union { float fv; unsigned u; } cv; cv.fv = f;
    unsigned u = cv.u;
    unsigned rnd = ((u >> 16) & 1u) + 0x7fffu;
    return (short)((u + rnd) >> 16);
}

// async 16B global->LDS (gfx950). Per-wave: uniform base + lane*16.
#define GLOAD_LDS16(gp, lp) __builtin_amdgcn_global_load_lds( \
    (const __attribute__((address_space(1))) unsigned int*)(gp), \
    (__attribute__((address_space(3))) unsigned int*)(lp), 16, 0, 0)

// Exact fp32 score — VERBATIM from the reference-matching lineage (do not
// reorder the summation: tie behavior vs the JAX argmax depends on it).
__device__ __forceinline__ float exact_score(const float4* __restrict__ zr,
                                             const float* __restrict__ embed,
                                             float h, int k)
{
    const float4* ep = (const float4*)(embed + (size_t)k * D_);
    float sa = 0.f, sb = 0.f;
    #pragma unroll
    for (int d4 = 0; d4 < 16; d4 += 2) {
        float4 ea = ep[d4], eb = ep[d4 + 1];
        sa += ea.x*zr[d4].x + ea.y*zr[d4].y + ea.z*zr[d4].z + ea.w*zr[d4].w;
        sb += eb.x*zr[d4+1].x + eb.y*zr[d4+1].y + eb.z*zr[d4+1].z + eb.w*zr[d4+1].w;
    }
    return (sa + sb) - h;
}

// ---- Kernel 1 (fused): blocks [0,256): 1x1 conv+BN -> ze fp32 + zbfT bf16
//      (conflict-free staging); blocks [256,768): embed -> XOR-swizzled
//      bf16 ebs + hn; block 256 zeroes outDiff. (cnt/cand/pbest removed.)
__global__ __launch_bounds__(256) void k_projprep(
    const float* __restrict__ z, const float* __restrict__ pw,
    const float* __restrict__ pb, const float* __restrict__ gamma,
    const float* __restrict__ beta, const float* __restrict__ rmean,
    const float* __restrict__ rvar, const float* __restrict__ embed,
    float* __restrict__ ze, short* __restrict__ zbfT,
    short* __restrict__ ebs, float* __restrict__ hn,
    float* __restrict__ outDiff)
{
    __shared__ float zt[128][64];   // [c][p] — straight copy of z tile (32 KB)
    __shared__ float wl[64][128];   // [d][c] — straight copy of W     (32 KB)
    const int tid = threadIdx.x;

    if (blockIdx.x >= 256) {
        // ---- prep: 512 blocks, t in [0, K*16) ----
        const int pbk = blockIdx.x - 256;
        int t = pbk * 256 + tid;
        float4 v = ((const float4*)embed)[t];
        float s = v.x*v.x + v.y*v.y + v.z*v.z + v.w*v.w;
        s += __shfl_xor(s, 1);
        s += __shfl_xor(s, 2);
        s += __shfl_xor(s, 4);
        s += __shfl_xor(s, 8);
        const int k = t >> 4, p = t & 15;
        if (p == 0) hn[k] = 0.5f * s;
        if (p < 8) {
            const int j = p ^ (k & 7);                  // XOR swizzle
            const float* src = embed + (size_t)k * D_ + j * 8;
            v8s o;
            #pragma unroll
            for (int i = 0; i < 8; ++i) o[i] = f2bf(src[i]);
            *(v8s*)(ebs + (size_t)k * D_ + p * 8) = o;
        }
        if (pbk == 0 && tid == 0) *outDiff = 0.f;       // zero diff scalar
        return;
    }

    // ---- proj: 256 blocks (fp32 tree identical to R2-lineage) ----
    const int n0  = blockIdx.x * 64;
    const int b   = n0 / HW_;
    const int hw0 = n0 % HW_;
    const float* zb = z + (size_t)b * C_ * HW_ + hw0;

    #pragma unroll
    for (int it = 0; it < 8; ++it) {
        int flat = tid + 256 * it;          // float4 units
        int c = flat >> 4, p4 = flat & 15;
        *(float4*)&zt[c][4*p4] = *(const float4*)&zb[c * HW_ + 4*p4];
    }
    #pragma unroll
    for (int it = 0; it < 8; ++it) {
        int flat = tid + 256 * it;
        int d = flat >> 5, c4i = flat & 31;
        *(float4*)&wl[d][4*c4i] = *(const float4*)&pw[d * C_ + 4*c4i];
    }
    __syncthreads();

    const int tp = tid & 15;
    const int td = tid >> 4;
    float acc[4][4] = {};
    #pragma unroll
    for (int c4 = 0; c4 < 32; ++c4) {
        float4 zq[4], wv[4];
        #pragma unroll
        for (int k = 0; k < 4; ++k) zq[k] = *(const float4*)&zt[4*c4 + k][4*tp];
        #pragma unroll
        for (int j = 0; j < 4; ++j) wv[j] = *(const float4*)&wl[4*td + j][4*c4];
        #pragma unroll
        for (int i = 0; i < 4; ++i)
            #pragma unroll
            for (int j = 0; j < 4; ++j)
                acc[i][j] += zq[0][i]*wv[j].x + zq[1][i]*wv[j].y
                           + zq[2][i]*wv[j].z + zq[3][i]*wv[j].w;
    }

    float sc[4], bi[4];
    #pragma unroll
    for (int j = 0; j < 4; ++j) {
        int d = 4*td + j;
        float s = gamma[d] / sqrtf(rvar[d] + 1e-5f);
        sc[j] = s;
        bi[j] = pb[d] * s + beta[d] - rmean[d] * s;
    }
    short* tbase = zbfT + (size_t)blockIdx.x * 4096;
    const int islot_base = (tp >> 2) * 2 + (td >> 3);
    const int lane_hi    = ((td >> 1) & 3) * 16;
    const int el0        = 4 * (td & 1);
    #pragma unroll
    for (int i = 0; i < 4; ++i) {
        int n = n0 + 4*tp + i;
        float4 o;
        o.x = acc[i][0]*sc[0] + bi[0];
        o.y = acc[i][1]*sc[1] + bi[1];
        o.z = acc[i][2]*sc[2] + bi[2];
        o.w = acc[i][3]*sc[3] + bi[3];
        *(float4*)&ze[(size_t)n * D_ + 4*td] = o;
        short4 ob;
        ob.x = f2bf(o.x); ob.y = f2bf(o.y); ob.z = f2bf(o.z); ob.w = f2bf(o.w);
        const int lane = lane_hi + ((4*tp + i) & 15);
        *(short4*)(tbase + islot_base * 512 + lane * 8 + el0) = ob;
    }
}

// ---- Kernel 2: megasweep — per block: 64 rows x ALL K codes, pass1 (max) +
//      pass2 (push to LDS candidates) + exact fp32 rescore + outputs.
//      Static LDS ~77 KB -> safe launch; grid 256 = one full round, no tail.
__global__ __launch_bounds__(512) void k_megasweep(
    const short* __restrict__ zbfT, const short* __restrict__ ebs,
    const float* __restrict__ hn, const float* __restrict__ ze,
    const float* __restrict__ embed, float* __restrict__ out0,
    float* __restrict__ outIdx, float* __restrict__ outDiff)
{
    __shared__ short EB[2][CHUNK * 64];       // 64 KB — double-buffered codes
    __shared__ float HL[2][CHUNK];            // 2 KB  — 0.5*||e||^2 per chunk
    __shared__ float vpart[8][ROWS];          // 2 KB  — per-wave row maxes
    __shared__ float vml[ROWS];               // thresholds (max - MARGIN)
    __shared__ int   cntL[ROWS];
    __shared__ int   candL[ROWS * CAND_CAP];  // 8 KB
    __shared__ int   bidxL[ROWS];
    __shared__ float dpart[8];

    const int tid  = threadIdx.x;
    const int lane = tid & 63;
    const int wv   = tid >> 6;        // [0,8)
    const int q    = lane >> 4;
    const int l15  = lane & 15;
    const int m8   = l15 & 7;
    const int bid  = blockIdx.x;
    const int n0   = bid * ROWS;

    // A fragments: identical for all 8 waves (same 64 rows). 8 coalesced b128.
    const short* aw = zbfT + (size_t)bid * 4096;
    v8s A[4][2];
    #pragma unroll
    for (int i = 0; i < 8; ++i)
        A[i >> 1][i & 1] = *(const v8s*)(aw + i * 512 + lane * 8);

    if (tid < ROWS) cntL[tid] = 0;

    // stage chunk 0 -> buf 0 (async) + its h-norms
    {
        const char* s_ = (const char*)ebs;
        char* l_ = (char*)&EB[0][0];
        #pragma unroll
        for (int i = 0; i < 4; ++i) {
            int seg = i * 8192 + tid * 16;
            GLOAD_LDS16(s_ + seg, l_ + seg);
        }
        if (tid < CHUNK) HL[0][tid] = hn[tid];
    }

    // lane-constant swizzled LDS read offsets (shorts) — matches ebs swizzle
    const int rb0 = l15 * 64 + ((q ^ m8) * 8);
    const int rb1 = l15 * 64 + (((q ^ m8) ^ 4) * 8);

    float best[4][4];
    float vm[4][4];
    #pragma unroll
    for (int rt = 0; rt < 4; ++rt)
        #pragma unroll
        for (int r = 0; r < 4; ++r) {
            best[rt][r] = -INFINITY;
            vm[rt][r]   = INFINITY;     // set for real after pass 1
        }

    __syncthreads();

    // 64 steps = pass1 chunks 0..31 (max), pass2 chunks 0..31 (push).
    // Per step: issue next-chunk stage, compute current, one barrier.
    #pragma unroll 1
    for (int s = 0; s < 2 * NCH; ++s) {
        const int cb = s & 1;
        if (s < 2 * NCH - 1) {
            const int nc = (s + 1) & (NCH - 1);
            const char* s_ = (const char*)(ebs + (size_t)nc * (CHUNK * 64));
            char* l_ = (char*)&EB[cb ^ 1][0];
            #pragma unroll
            for (int i = 0; i < 4; ++i) {
                int seg = i * 8192 + tid * 16;
                GLOAD_LDS16(s_ + seg, l_ + seg);
            }
            if (tid < CHUNK) HL[cb ^ 1][tid] = hn[nc * CHUNK + tid];
        }
        const short* ebp = &EB[cb][0];
        const float* hlp = &HL[cb][0];

        if (s < NCH) {
            // ---- pass 1: accumulate bf16 row max (wave handles 32 codes) --
            #pragma unroll
            for (int ti = 0; ti < 2; ++ti) {
                const int t = wv * 2 + ti;
                v8s B0 = *(const v8s*)(ebp + rb0 + t * 1024);
                v8s B1 = *(const v8s*)(ebp + rb1 + t * 1024);
                const float mh = -hlp[t * 16 + l15];
                #pragma unroll
                for (int rt = 0; rt < 4; ++rt) {
                    v4f c = {mh, mh, mh, mh};
                    c = __builtin_amdgcn_mfma_f32_16x16x32_bf16(A[rt][0], B0, c, 0, 0, 0);
                    c = __builtin_amdgcn_mfma_f32_16x16x32_bf16(A[rt][1], B1, c, 0, 0, 0);
                    #pragma unroll
                    for (int r = 0; r < 4; ++r) best[rt][r] = fmaxf(best[rt][r], c[r]);
                }
            }
        } else {
            // ---- pass 2: recompute (bitwise-identical) and push candidates
            const int codeBase = (s & (NCH - 1)) * CHUNK;
            #pragma unroll
            for (int ti = 0; ti < 2; ++ti) {
                const int t = wv * 2 + ti;
                v8s B0 = *(const v8s*)(ebp + rb0 + t * 1024);
                v8s B1 = *(const v8s*)(ebp + rb1 + t * 1024);
                const float mh = -hlp[t * 16 + l15];
                #pragma unroll
                for (int rt = 0; rt < 4; ++rt) {
                    v4f c = {mh, mh, mh, mh};
                    c = __builtin_amdgcn_mfma_f32_16x16x32_bf16(A[rt][0], B0, c, 0, 0, 0);
                    c = __builtin_amdgcn_mfma_f32_16x16x32_bf16(A[rt][1], B1, c, 0, 0, 0);
                    bool a0 = c[0] > vm[rt][0];
                    bool a1 = c[1] > vm[rt][1];
                    bool a2 = c[2] > vm[rt][2];
                    bool a3 = c[3] > vm[rt][3];
                    if (a0 | a1 | a2 | a3) {
                        const int code = codeBase + t * 16 + l15;
                        const int row0 = rt * 16 + q * 4;
                        #pragma unroll
                        for (int r = 0; r < 4; ++r) {
                            if (c[r] > vm[rt][r]) {
                                int sl = atomicAdd(&cntL[row0 + r], 1);
                                if (sl < CAND_CAP) candL[(row0 + r) * CAND_CAP + sl] = code;
                            }
                        }
                    }
                }
            }
        }
        __syncthreads();

        if (s == NCH - 1) {
            // global (all-K) row max -> threshold. Same value as old cross-split Vm.
            #pragma unroll
            for (int rt = 0; rt < 4; ++rt)
                #pragma unroll
                for (int r = 0; r < 4; ++r) {
                    float v = best[rt][r];
                    v = fmaxf(v, __shfl_xor(v, 1));
                    v = fmaxf(v, __shfl_xor(v, 2));
                    v = fmaxf(v, __shfl_xor(v, 4));
                    v = fmaxf(v, __shfl_xor(v, 8));
                    if (l15 == 0) vpart[wv][rt * 16 + q * 4 + r] = v;
                }
            __syncthreads();
            if (tid < ROWS) {
                float v = vpart[0][tid];
                #pragma unroll
                for (int w = 1; w < 8; ++w) v = fmaxf(v, vpart[w][tid]);
                vml[tid] = v - MARGIN;
            }
            __syncthreads();
            #pragma unroll
            for (int rt = 0; rt < 4; ++rt)
                #pragma unroll
                for (int r = 0; r < 4; ++r)
                    vm[rt][r] = vml[rt * 16 + q * 4 + r];
        }
    }

    // ---- exact fp32 rescore: 8 rows per wave (lanes 0..7), verbatim scoring
    if (lane < 8) {
        const int r = wv * 8 + lane;
        const int n = n0 + r;
        float4 zr[16];
        const float4* zp = (const float4*)(ze + (size_t)n * D_);
        #pragma unroll
        for (int i = 0; i < 16; ++i) zr[i] = zp[i];

        const int m = cntL[r];
        float bestv = -INFINITY;
        int   bidx  = 0x7fffffff;
        if (m == 0 || m > CAND_CAP) {
            // safety net: screen anomaly -> full exact scan, ascending k
            for (int k = 0; k < K_; ++k) {
                float sc = exact_score(zr, embed, hn[k], k);
                if (sc > bestv) { bestv = sc; bidx = k; }
            }
        } else {
            for (int i = 0; i < m; ++i) {
                int k = candL[r * CAND_CAP + i];
                float sc = exact_score(zr, embed, hn[k], k);
                if (sc > bestv || (sc == bestv && k < bidx)) { bestv = sc; bidx = k; }
            }
        }
        if (bidx == 0x7fffffff) bidx = 0;
        bidxL[r] = bidx;
        outIdx[n] = (float)bidx;
    }
    __syncthreads();

    // ---- z_q gather into LDS (reuse EB, stride-65 pad) + diff partials ----
    float* zq = (float*)&EB[0][0];            // [64][65] floats, 16.6 KB
    {
        const int r = tid >> 3, j = tid & 7;  // 64 rows x 8 segments of 8 dims
        const int bx = bidxL[r];
        const float4* eq = (const float4*)(embed + (size_t)bx * D_ + j * 8);
        float4 e0 = eq[0], e1 = eq[1];
        const float4* zp = (const float4*)(ze + (size_t)(n0 + r) * D_ + j * 8);
        float4 z0 = zp[0], z1 = zp[1];
        float* zd = zq + r * 65 + j * 8;
        zd[0] = e0.x; zd[1] = e0.y; zd[2] = e0.z; zd[3] = e0.w;
        zd[4] = e1.x; zd[5] = e1.y; zd[6] = e1.z; zd[7] = e1.w;
        float dx, local = 0.f;
        dx = e0.x - z0.x; local += dx * dx;
        dx = e0.y - z0.y; local += dx * dx;
        dx = e0.z - z0.z; local += dx * dx;
        dx = e0.w - z0.w; local += dx * dx;
        dx = e1.x - z1.x; local += dx * dx;
        dx = e1.y - z1.y; local += dx * dx;
        dx = e1.z - z1.z; local += dx * dx;
        dx = e1.w - z1.w; local += dx * dx;
        local += __shfl_xor(local, 1);
        local += __shfl_xor(local, 2);
        local += __shfl_xor(local, 4);
        local += __shfl_xor(local, 8);
        local += __shfl_xor(local, 16);
        local += __shfl_xor(local, 32);
        if (lane == 0) dpart[wv] = local;
    }
    __syncthreads();
    if (tid == 0) {
        float v = 0.f;
        #pragma unroll
        for (int w = 0; w < 8; ++w) v += dpart[w];
        atomicAdd(outDiff, v * (12.5f / (float)(N_ * D_)));
    }

    // ---- transposed coalesced out0 write: [b][d][hw], 256B/wave segments --
    {
        const int b = n0 >> 10, hw0 = n0 & 1023;
        float* ob = out0 + (size_t)b * (D_ * HW_) + hw0;
        #pragma unroll
        for (int i = 0; i < 8; ++i) {
            int flat = i * 512 + tid;
            int d = flat >> 6, hh = flat & 63;
            ob[d * HW_ + hh] = zq[hh * 65 + d];
        }
    }
}

extern "C" void kernel_launch(void* const* d_in, const int* in_sizes, int n_in,
                              void* d_out, int out_size, void* d_ws, size_t ws_size,
                              hipStream_t stream)
{
    const float* z     = (const float*)d_in[0];
    const float* pw    = (const float*)d_in[1];
    const float* pb    = (const float*)d_in[2];
    const float* gamma = (const float*)d_in[3];
    const float* beta  = (const float*)d_in[4];
    const float* rmean = (const float*)d_in[5];
    const float* rvar  = (const float*)d_in[6];
    const float* embed = (const float*)d_in[7];

    float* out = (float*)d_out;
    float* out0    = out;                     // [B,D,H,W]
    float* outDiff = out + (size_t)N_ * D_;   // scalar
    float* outIdx  = outDiff + 1;             // [B,H,W]

    // Workspace layout (pbest/cnt/cand eliminated — candidates live in LDS)
    float* ws    = (float*)d_ws;
    float* ze    = ws;                                   // N*64 f   (4 MB)
    short* zbfT  = (short*)(ze + (size_t)N_ * D_);       // N*64 s   (2 MB, tiled)
    short* ebs   = zbfT + (size_t)N_ * D_;               // K*64 s   (1 MB)
    float* hn    = (float*)(ebs + (size_t)K_ * D_);      // K        (32 KB)

    k_projprep<<<256 + 512, 256, 0, stream>>>(z, pw, pb, gamma, beta, rmean,
                                              rvar, embed, ze, zbfT, ebs, hn,
                                              outDiff);
    k_megasweep<<<N_ / ROWS, 512, 0, stream>>>(zbfT, ebs, hn, ze, embed,
                                               out0, outIdx, outDiff);
}

// Round 3
// 137.056 us; speedup vs baseline: 1.2491x; 1.2491x over previous
//
#include <hip/hip_runtime.h>
#include <math.h>

// Problem constants
#define B_   16
#define C_   128
#define H_   32
#define W_   32
#define D_   64
#define K_   8192
#define HW_  (H_*W_)       // 1024
#define N_   (B_*HW_)      // 16384

// MFMA sweep config — whole split staged once, zero in-loop barriers,
// 512-row blocks. (Reverted from R1/R2 megasweep: 1-block/CU + per-step
// drain barrier was latency-exposed — 90 µs, MfmaUtil 14%.)
#define CS      32         // code splits (grid.y)
#define CPB     (K_/CS)    // 256 codes per block
#define ROWS_PB 512        // rows per block (8 waves x 64 rows)
// Worst-case bf16 screen error bound; 0.12 margin, E[cands/row] ~ 1.9.
#define MARGIN  0.12f
#define CAND_CAP 32

typedef short v8s __attribute__((ext_vector_type(8)));
typedef float v4f __attribute__((ext_vector_type(4)));

__device__ __forceinline__ short f2bf(float f) {   // RNE fp32 -> bf16
    union { float fv; unsigned u; } cv; cv.fv = f;
    unsigned u = cv.u;
    unsigned rnd = ((u >> 16) & 1u) + 0x7fffu;
    return (short)((u + rnd) >> 16);
}

// async 16B global->LDS (gfx950). Per-wave: uniform base + lane*16.
#define GLOAD_LDS16(gp, lp) __builtin_amdgcn_global_load_lds( \
    (const __attribute__((address_space(1))) unsigned int*)(gp), \
    (__attribute__((address_space(3))) unsigned int*)(lp), 16, 0, 0)

// Exact fp32 score — VERBATIM reference-matching lineage (do not reorder).
__device__ __forceinline__ float exact_score(const float4* __restrict__ zr,
                                             const float* __restrict__ embed,
                                             float h, int k)
{
    const float4* ep = (const float4*)(embed + (size_t)k * D_);
    float sa = 0.f, sb = 0.f;
    #pragma unroll
    for (int d4 = 0; d4 < 16; d4 += 2) {
        float4 ea = ep[d4], eb = ep[d4 + 1];
        sa += ea.x*zr[d4].x + ea.y*zr[d4].y + ea.z*zr[d4].z + ea.w*zr[d4].w;
        sb += eb.x*zr[d4+1].x + eb.y*zr[d4+1].y + eb.z*zr[d4+1].z + eb.w*zr[d4+1].w;
    }
    return (sa + sb) - h;
}

// ---- Kernel 1 (fused): blocks [0,256): 1x1 conv+BN -> ze fp32 + zbfT bf16
//      (conflict-free staging); blocks [256,768): embed -> XOR-swizzled
//      bf16 ebs + hn; first 64 prep blocks also zero cnt, block 256 zeroes
//      outDiff.
__global__ __launch_bounds__(256) void k_projprep(
    const float* __restrict__ z, const float* __restrict__ pw,
    const float* __restrict__ pb, const float* __restrict__ gamma,
    const float* __restrict__ beta, const float* __restrict__ rmean,
    const float* __restrict__ rvar, const float* __restrict__ embed,
    float* __restrict__ ze, short* __restrict__ zbfT,
    short* __restrict__ ebs, float* __restrict__ hn,
    int* __restrict__ cnt, float* __restrict__ outDiff)
{
    __shared__ float zt[128][64];   // [c][p] — straight copy of z tile (32 KB)
    __shared__ float wl[64][128];   // [d][c] — straight copy of W     (32 KB)
    const int tid = threadIdx.x;

    if (blockIdx.x >= 256) {
        // ---- prep: 512 blocks, t in [0, K*16) ----
        const int pbk = blockIdx.x - 256;
        int t = pbk * 256 + tid;
        float4 v = ((const float4*)embed)[t];
        float s = v.x*v.x + v.y*v.y + v.z*v.z + v.w*v.w;
        s += __shfl_xor(s, 1);
        s += __shfl_xor(s, 2);
        s += __shfl_xor(s, 4);
        s += __shfl_xor(s, 8);
        const int k = t >> 4, p = t & 15;
        if (p == 0) hn[k] = 0.5f * s;
        if (p < 8) {
            const int j = p ^ (k & 7);                  // XOR swizzle
            const float* src = embed + (size_t)k * D_ + j * 8;
            v8s o;
            #pragma unroll
            for (int i = 0; i < 8; ++i) o[i] = f2bf(src[i]);
            *(v8s*)(ebs + (size_t)k * D_ + p * 8) = o;
        }
        if (pbk < 64) cnt[pbk * 256 + tid] = 0;         // zero counters
        if (pbk == 0 && tid == 0) *outDiff = 0.f;       // zero diff scalar
        return;
    }

    // ---- proj: 256 blocks (fp32 tree identical to R2-lineage) ----
    const int n0  = blockIdx.x * 64;
    const int b   = n0 / HW_;
    const int hw0 = n0 % HW_;
    const float* zb = z + (size_t)b * C_ * HW_ + hw0;

    #pragma unroll
    for (int it = 0; it < 8; ++it) {
        int flat = tid + 256 * it;          // float4 units
        int c = flat >> 4, p4 = flat & 15;
        *(float4*)&zt[c][4*p4] = *(const float4*)&zb[c * HW_ + 4*p4];
    }
    #pragma unroll
    for (int it = 0; it < 8; ++it) {
        int flat = tid + 256 * it;
        int d = flat >> 5, c4i = flat & 31;
        *(float4*)&wl[d][4*c4i] = *(const float4*)&pw[d * C_ + 4*c4i];
    }
    __syncthreads();

    const int tp = tid & 15;
    const int td = tid >> 4;
    float acc[4][4] = {};
    #pragma unroll
    for (int c4 = 0; c4 < 32; ++c4) {
        float4 zq[4], wv[4];
        #pragma unroll
        for (int k = 0; k < 4; ++k) zq[k] = *(const float4*)&zt[4*c4 + k][4*tp];
        #pragma unroll
        for (int j = 0; j < 4; ++j) wv[j] = *(const float4*)&wl[4*td + j][4*c4];
        #pragma unroll
        for (int i = 0; i < 4; ++i)
            #pragma unroll
            for (int j = 0; j < 4; ++j)
                acc[i][j] += zq[0][i]*wv[j].x + zq[1][i]*wv[j].y
                           + zq[2][i]*wv[j].z + zq[3][i]*wv[j].w;
    }

    float sc[4], bi[4];
    #pragma unroll
    for (int j = 0; j < 4; ++j) {
        int d = 4*td + j;
        float s = gamma[d] / sqrtf(rvar[d] + 1e-5f);
        sc[j] = s;
        bi[j] = pb[d] * s + beta[d] - rmean[d] * s;
    }
    short* tbase = zbfT + (size_t)blockIdx.x * 4096;
    const int islot_base = (tp >> 2) * 2 + (td >> 3);
    const int lane_hi    = ((td >> 1) & 3) * 16;
    const int el0        = 4 * (td & 1);
    #pragma unroll
    for (int i = 0; i < 4; ++i) {
        int n = n0 + 4*tp + i;
        float4 o;
        o.x = acc[i][0]*sc[0] + bi[0];
        o.y = acc[i][1]*sc[1] + bi[1];
        o.z = acc[i][2]*sc[2] + bi[2];
        o.w = acc[i][3]*sc[3] + bi[3];
        *(float4*)&ze[(size_t)n * D_ + 4*td] = o;
        short4 ob;
        ob.x = f2bf(o.x); ob.y = f2bf(o.y); ob.z = f2bf(o.z); ob.w = f2bf(o.w);
        const int lane = lane_hi + ((4*tp + i) & 15);
        *(short4*)(tbase + islot_base * 512 + lane * 8 + el0) = ob;
    }
}

// ---- Kernel 2: MFMA bf16 sweep — 512 rows/block, whole split in LDS,
//      single barrier; PUSH computes Vm in-prologue from pbest ------------
template<bool PUSH>
__global__ __launch_bounds__(512) void k_sweep(
    const short* __restrict__ zbfT, const short* __restrict__ ebs,
    const float* __restrict__ hn, float* __restrict__ pbest,
    int* __restrict__ cnt, int* __restrict__ cand)
{
    __shared__ short eb[CPB * 64];    // 32 KB — entire split, swizzled
    __shared__ float hl[CPB];         // 1 KB
    __shared__ float vml[ROWS_PB];    // 2 KB — per-row threshold (PUSH)
    const int tid  = threadIdx.x;
    const int lane = tid & 63;
    const int wv   = tid >> 6;        // [0,8)
    const int q    = lane >> 4;
    const int l15  = lane & 15;
    const int m8   = l15 & 7;
    const int rowBase = blockIdx.x * ROWS_PB + wv * 64;
    const int code0   = blockIdx.y * CPB;

    // stage entire split: linear 32 KB copy (async, no VGPR round-trip)
    {
        const char* s_ = (const char*)(ebs + (size_t)code0 * 64);
        char* l_ = (char*)&eb[0];
        #pragma unroll
        for (int i = 0; i < 4; ++i) {
            int seg = (wv * 4 + i) * 1024 + lane * 16;
            GLOAD_LDS16(s_ + seg, l_ + seg);
        }
        if (tid < CPB) hl[tid] = hn[code0 + tid];
    }

    // PUSH: cooperative Vm: thread tid owns row blockIdx.x*512 + tid
    if (PUSH) {
        float v = -INFINITY;
        const int row = blockIdx.x * ROWS_PB + tid;
        #pragma unroll
        for (int s = 0; s < CS; ++s) v = fmaxf(v, pbest[(size_t)s * N_ + row]);
        vml[tid] = v - MARGIN;
    }

    // A fragments from tiled zbfT: 8 coalesced b128 per lane
    const short* aw = zbfT + (size_t)(blockIdx.x * 8 + wv) * 4096;
    v8s A[4][2];
    #pragma unroll
    for (int i = 0; i < 8; ++i)
        A[i >> 1][i & 1] = *(const v8s*)(aw + i * 512 + lane * 8);

    // lane-constant swizzled LDS read offsets (shorts)
    const int rb0 = l15 * 64 + ((q ^ m8) * 8);
    const int rb1 = l15 * 64 + (((q ^ m8) ^ 4) * 8);

    __syncthreads();    // the ONLY barrier

    float best[4][4];
    float vm[4][4];
    if (PUSH) {
        #pragma unroll
        for (int rt = 0; rt < 4; ++rt)
            #pragma unroll
            for (int r = 0; r < 4; ++r)
                vm[rt][r] = vml[wv * 64 + rt*16 + q*4 + r];
    } else {
        #pragma unroll
        for (int rt = 0; rt < 4; ++rt)
            #pragma unroll
            for (int r = 0; r < 4; ++r) best[rt][r] = -INFINITY;
    }

    #pragma unroll 1    // I$: keep body small
    for (int tc = 0; tc < 2; ++tc) {
        #pragma unroll
        for (int ti = 0; ti < 8; ++ti) {
            const int t = tc * 8 + ti;
            v8s B0 = *(const v8s*)(&eb[0] + rb0 + t * 1024);
            v8s B1 = *(const v8s*)(&eb[0] + rb1 + t * 1024);
            const float mh = -hl[t * 16 + l15];
            #pragma unroll
            for (int rt = 0; rt < 4; ++rt) {
                v4f c = {mh, mh, mh, mh};
                c = __builtin_amdgcn_mfma_f32_16x16x32_bf16(A[rt][0], B0, c, 0, 0, 0);
                c = __builtin_amdgcn_mfma_f32_16x16x32_bf16(A[rt][1], B1, c, 0, 0, 0);
                if (!PUSH) {
                    #pragma unroll
                    for (int r = 0; r < 4; ++r) best[rt][r] = fmaxf(best[rt][r], c[r]);
                } else {
                    bool a0 = c[0] > vm[rt][0];
                    bool a1 = c[1] > vm[rt][1];
                    bool a2 = c[2] > vm[rt][2];
                    bool a3 = c[3] > vm[rt][3];
                    if (a0 | a1 | a2 | a3) {
                        const int code = code0 + t * 16 + l15;
                        const int row0 = rowBase + rt*16 + q*4;
                        #pragma unroll
                        for (int r = 0; r < 4; ++r) {
                            if (c[r] > vm[rt][r]) {
                                int s = atomicAdd(&cnt[row0 + r], 1);
                                if (s < CAND_CAP) cand[(row0 + r) * CAND_CAP + s] = code;
                            }
                        }
                    }
                }
            }
        }
    }

    if (!PUSH) {
        #pragma unroll
        for (int rt = 0; rt < 4; ++rt)
            #pragma unroll
            for (int r = 0; r < 4; ++r) {
                float v = best[rt][r];
                v = fmaxf(v, __shfl_xor(v, 1));
                v = fmaxf(v, __shfl_xor(v, 2));
                v = fmaxf(v, __shfl_xor(v, 4));
                v = fmaxf(v, __shfl_xor(v, 8));
                if (l15 == 0)
                    pbest[(size_t)blockIdx.y * N_ + rowBase + rt*16 + q*4 + r] = v;
            }
    }
}

// ---- Kernel 3: exact fp32 rescore + outputs + diff ------------------------
//      NEW: 256 blocks x 256 threads (4 waves/CU on all CUs, vs old 1 wave).
//      4 lanes per row score candidates in parallel; lex-max (score, -k)
//      reduce == old serial tie-break (order-independent). Epilogue = the
//      R2-verified LDS-transpose + coalesced out0 write.
__global__ __launch_bounds__(256) void k_pick(
    const int* __restrict__ cnt, const int* __restrict__ cand,
    const float* __restrict__ embed, const float* __restrict__ hn,
    const float* __restrict__ ze, float* __restrict__ out0,
    float* __restrict__ outIdx, float* __restrict__ outDiff)
{
    __shared__ float zqs[64 * 65];    // [64][65] transpose buffer (16.6 KB)
    __shared__ int   bidxL[64];
    __shared__ float dpart[4];

    const int tid  = threadIdx.x;
    const int lane = tid & 63;
    const int wv   = tid >> 6;
    const int r    = tid >> 2;        // row within block [0,64)
    const int slot = tid & 3;         // candidate slot [0,4)
    const int n0   = blockIdx.x * 64;
    const int n    = n0 + r;

    // full row in regs (4 slots redundantly load same row; L1/L2-served)
    float4 zr[16];
    const float4* zp = (const float4*)(ze + (size_t)n * D_);
    #pragma unroll
    for (int i = 0; i < 16; ++i) zr[i] = zp[i];

    const int m = cnt[n];
    float best = -INFINITY;
    int   bidx = 0x7fffffff;
    if (m == 0 || m > CAND_CAP) {
        // safety net: screen anomaly -> full exact scan, strided over slots.
        // lex rule (max s, min k) == old ascending-k first-max.
        for (int k = slot; k < K_; k += 4) {
            float s = exact_score(zr, embed, hn[k], k);
            if (s > best || (s == best && k < bidx)) { best = s; bidx = k; }
        }
    } else {
        for (int i = slot; i < m; i += 4) {
            int k = cand[n * CAND_CAP + i];
            float s = exact_score(zr, embed, hn[k], k);
            if (s > best || (s == best && k < bidx)) { best = s; bidx = k; }
        }
    }
    // reduce across the 4 slots (xor 1,2 stays inside the quad)
    #pragma unroll
    for (int d = 1; d < 4; d <<= 1) {
        float ob = __shfl_xor(best, d);
        int   oi = __shfl_xor(bidx, d);
        if (ob > best || (ob == best && oi < bidx)) { best = ob; bidx = oi; }
    }
    if (bidx == 0x7fffffff) bidx = 0;
    if (slot == 0) { bidxL[r] = bidx; outIdx[n] = (float)bidx; }
    __syncthreads();

    // ---- z_q gather into LDS (stride-65 pad) + diff partials -------------
    {
        const int j  = slot;                      // 16 floats per thread
        const int bx = bidxL[r];
        const float4* eq  = (const float4*)(embed + (size_t)bx * D_ + j * 16);
        const float4* zp2 = (const float4*)(ze + (size_t)(n0 + r) * D_ + j * 16);
        float* zd = zqs + r * 65 + j * 16;
        float local = 0.f;
        #pragma unroll
        for (int t = 0; t < 4; ++t) {
            float4 e = eq[t], zv = zp2[t];
            zd[4*t + 0] = e.x; zd[4*t + 1] = e.y;
            zd[4*t + 2] = e.z; zd[4*t + 3] = e.w;
            float dx = e.x - zv.x, dy = e.y - zv.y;
            float dz = e.z - zv.z, dw = e.w - zv.w;
            local += dx*dx + dy*dy + dz*dz + dw*dw;
        }
        local += __shfl_xor(local, 1);
        local += __shfl_xor(local, 2);
        local += __shfl_xor(local, 4);
        local += __shfl_xor(local, 8);
        local += __shfl_xor(local, 16);
        local += __shfl_xor(local, 32);
        if (lane == 0) dpart[wv] = local;
    }
    __syncthreads();
    if (tid == 0) {
        float v = dpart[0] + dpart[1] + dpart[2] + dpart[3];
        atomicAdd(outDiff, v * (12.5f / (float)(N_ * D_)));
    }

    // ---- transposed coalesced out0 write: 256B/wave segments -------------
    {
        const int b = n0 >> 10, hw0 = n0 & 1023;
        float* ob = out0 + (size_t)b * (D_ * HW_) + hw0;
        #pragma unroll
        for (int i = 0; i < 16; ++i) {
            int flat = i * 256 + tid;
            int d = flat >> 6, hh = flat & 63;
            ob[d * HW_ + hh] = zqs[hh * 65 + d];
        }
    }
}

extern "C" void kernel_launch(void* const* d_in, const int* in_sizes, int n_in,
                              void* d_out, int out_size, void* d_ws, size_t ws_size,
                              hipStream_t stream)
{
    const float* z     = (const float*)d_in[0];
    const float* pw    = (const float*)d_in[1];
    const float* pb    = (const float*)d_in[2];
    const float* gamma = (const float*)d_in[3];
    const float* beta  = (const float*)d_in[4];
    const float* rmean = (const float*)d_in[5];
    const float* rvar  = (const float*)d_in[6];
    const float* embed = (const float*)d_in[7];

    float* out = (float*)d_out;
    float* out0    = out;                     // [B,D,H,W]
    float* outDiff = out + (size_t)N_ * D_;   // scalar
    float* outIdx  = outDiff + 1;             // [B,H,W]

    // Workspace layout
    float* ws    = (float*)d_ws;
    float* ze    = ws;                                   // N*64 f   (4 MB)
    short* zbfT  = (short*)(ze + (size_t)N_ * D_);       // N*64 s   (2 MB, tiled)
    short* ebs   = zbfT + (size_t)N_ * D_;               // K*64 s   (1 MB)
    float* hn    = (float*)(ebs + (size_t)K_ * D_);      // K        (32 KB)
    float* pbest = hn + K_;                              // CS*N     (2 MB)
    int*   cnt   = (int*)(pbest + (size_t)CS * N_);      // N        (64 KB)
    int*   cand  = cnt + N_;                             // N*32     (2 MB)

    k_projprep<<<256 + 512, 256, 0, stream>>>(z, pw, pb, gamma, beta, rmean,
                                              rvar, embed, ze, zbfT, ebs, hn,
                                              cnt, outDiff);
    k_sweep<false><<<dim3(N_ / ROWS_PB, CS), 512, 0, stream>>>(
        zbfT, ebs, hn, pbest, nullptr, nullptr);
    k_sweep<true><<<dim3(N_ / ROWS_PB, CS), 512, 0, stream>>>(
        zbfT, ebs, hn, pbest, cnt, cand);
    k_pick<<<N_ / 64, 256, 0, stream>>>(cnt, cand, embed, hn, ze, out0,
                                        outIdx, outDiff);
}